// Round 13
// baseline (446.525 us; speedup 1.0000x reference)
//
#include <hip/hip_runtime.h>
#include <cstdint>
#include <cstddef>

// ---------------------------------------------------------------------------
// GraphAttentionHead: out = elu(softmax(mask(LeakyReLU(mu_i + xi_j))) @ h)
// Round 24: A-BUILD SOFTWARE PIPELINE (one window ahead).
//   Ledger re-fit over R10-R23: the windowed MFMA loop itself = ~90us in
//   every variant (91 with bitmask input, 135 with in-loop adj = 90+45,
//   132 two-phase = 45 stream + ~87 loop). Phase 2 has NO memory dependence
//   (bits/E/F in LDS, ht L2-resident) -> last unfalsified mechanism: the
//   serial per-window VALU(A-build ~280cyc) -> MFMA(~256cyc) chain in
//   barrier-locked waves (pipes alternate idle; m114 overlap never forms).
//   k_gatt19 = gatt18 with af(win+1) built DURING win's MFMA quarters
//   (inputs are phase-1-static; zero dependence on current staging).
//   +16 VGPR. Everything else identical to R23.
// ---------------------------------------------------------------------------

#define LOG2E 1.44269504f

typedef __attribute__((ext_vector_type(8))) short short8;   // 8 bf16 = 4 VGPRs
typedef __attribute__((ext_vector_type(4))) float floatx4;  // MFMA acc

using uint_as1 = __attribute__((address_space(1))) unsigned int;
using uint_as3 = __attribute__((address_space(3))) unsigned int;

__device__ __forceinline__ void gld_lds16(const void* g, void* l) {
  __builtin_amdgcn_global_load_lds((const uint_as1*)g, (uint_as3*)l, 16, 0, 0);
}

__device__ __forceinline__ unsigned short f2b(float f) {  // fp32 -> bf16 RNE (finite)
  unsigned u = __float_as_uint(f);
  u += 0x7fffu + ((u >> 16) & 1u);
  return (unsigned short)(u >> 16);
}

// packed RNE convert: lo16 = bf16(a), hi16 = bf16(b) — single VALU op
__device__ __forceinline__ unsigned cvtpk_bf16(float a, float b) {
  unsigned r;
  asm("v_cvt_pk_bf16_f32 %0, %1, %2" : "=v"(r) : "v"(a), "v"(b));
  return r;
}

// ------------------- K0b: W_phi [512][256] -> Wt bf16 [256][512] ------------
__global__ void k_prep_wt(const float* __restrict__ w, unsigned short* __restrict__ wt) {
  int tid = blockIdx.x * 256 + threadIdx.x;
  int n = tid >> 9, k = tid & 511;
  wt[n * 512 + k] = f2b(w[k * 256 + n]);
}

// ------ K1: h_t = (features @ W_phi)^T (bf16 MFMA) + mu/xi partials ---------
__global__ __launch_bounds__(256, 2) void k_gemm1m(const float* __restrict__ f,
                                                   const unsigned short* __restrict__ wt,
                                                   const float* __restrict__ wmu,
                                                   const float* __restrict__ wxi,
                                                   unsigned short* __restrict__ ht,
                                                   float* __restrict__ mupart,
                                                   float* __restrict__ xipart) {
  __shared__ __align__(16) unsigned short As[64 * 64];
  __shared__ __align__(16) unsigned short Bs[128 * 64];
  __shared__ float musum[4][64];
  __shared__ float xisum[4][64];
  int t = threadIdx.x, w = t >> 6, l = t & 63;
  int bm_ = blockIdx.x >> 1, bn = blockIdx.x & 1;
  int m0 = bm_ * 64, n0 = bn * 128;
  int lr = l >> 3, lg = l & 7, g = lg ^ lr;
  int kg = l >> 4, ln = l & 15;
  floatx4 zero = {0.f, 0.f, 0.f, 0.f};
  floatx4 acc[4][2];
#pragma unroll
  for (int mf = 0; mf < 4; ++mf)
#pragma unroll
    for (int nf = 0; nf < 2; ++nf) acc[mf][nf] = zero;

  for (int it = 0; it < 8; ++it) {
    int k0 = it * 64;
#pragma unroll
    for (int q = 0; q < 2; ++q) {
      int row = w * 16 + q * 8 + lr;
      const float* fp = f + (size_t)(m0 + row) * 512 + k0 + g * 8;
      float4 v0 = *(const float4*)fp;
      float4 v1 = *(const float4*)(fp + 4);
      uint4 d = {cvtpk_bf16(v0.x, v0.y), cvtpk_bf16(v0.z, v0.w),
                 cvtpk_bf16(v1.x, v1.y), cvtpk_bf16(v1.z, v1.w)};
      *(uint4*)&As[row * 64 + lg * 8] = d;
    }
#pragma unroll
    for (int q = 0; q < 4; ++q) {
      int row = w * 32 + q * 8 + lr;
      const void* gp = wt + (size_t)(n0 + row) * 512 + k0 + g * 8;
      int lb = __builtin_amdgcn_readfirstlane((w * 32 + q * 8) * 64);
      gld_lds16(gp, &Bs[lb]);
    }
    __syncthreads();
#pragma unroll
    for (int ks = 0; ks < 2; ++ks) {
      int gg = ks * 4 + kg;
      int swz = (gg ^ (ln & 7)) * 8;
      short8 bfr[2];
#pragma unroll
      for (int nf = 0; nf < 2; ++nf)
        bfr[nf] = *(const short8*)&Bs[(w * 32 + nf * 16 + ln) * 64 + swz];
#pragma unroll
      for (int mf = 0; mf < 4; ++mf) {
        short8 afr = *(const short8*)&As[(mf * 16 + ln) * 64 + swz];
#pragma unroll
        for (int nf = 0; nf < 2; ++nf)
          acc[mf][nf] = __builtin_amdgcn_mfma_f32_16x16x32_bf16(afr, bfr[nf], acc[mf][nf], 0, 0, 0);
      }
    }
    __syncthreads();
  }
#pragma unroll
  for (int mf = 0; mf < 4; ++mf)
#pragma unroll
    for (int nf = 0; nf < 2; ++nf) {
      int ng = n0 + w * 32 + nf * 16 + ln;
      int mg = m0 + mf * 16 + kg * 4;
      ushort4 o = {f2b(acc[mf][nf][0]), f2b(acc[mf][nf][1]),
                   f2b(acc[mf][nf][2]), f2b(acc[mf][nf][3])};
      *(ushort4*)&ht[(size_t)ng * 8192 + mg] = o;
    }
  float wma = wmu[n0 + w * 32 + ln], wmb = wmu[n0 + w * 32 + 16 + ln];
  float wxa = wxi[n0 + w * 32 + ln], wxb = wxi[n0 + w * 32 + 16 + ln];
#pragma unroll
  for (int mf = 0; mf < 4; ++mf)
#pragma unroll
    for (int r = 0; r < 4; ++r) {
      float ms = acc[mf][0][r] * wma + acc[mf][1][r] * wmb;
      float xs = acc[mf][0][r] * wxa + acc[mf][1][r] * wxb;
      ms += __shfl_xor(ms, 1); ms += __shfl_xor(ms, 2);
      ms += __shfl_xor(ms, 4); ms += __shfl_xor(ms, 8);
      xs += __shfl_xor(xs, 1); xs += __shfl_xor(xs, 2);
      xs += __shfl_xor(xs, 4); xs += __shfl_xor(xs, 8);
      if (ln == 0) {
        musum[w][mf * 16 + kg * 4 + r] = ms;
        xisum[w][mf * 16 + kg * 4 + r] = xs;
      }
    }
  __syncthreads();
  if (t < 64) {
    float m_ = musum[0][t] + musum[1][t] + musum[2][t] + musum[3][t];
    mupart[(size_t)bn * 8192 + m0 + t] = m_;
  } else if (t < 128) {
    int r = t - 64;
    float x_ = xisum[0][r] + xisum[1][r] + xisum[2][r] + xisum[3][r];
    xipart[(size_t)bn * 8192 + m0 + r] = x_;
  }
}

// ------------- K3: two-phase fused attention, pipelined A-build -------------
// grid 256 = 8 jb x 32 ig. Block 256i x 256n x 1024j; 8 waves i-split,
// wave 32i x 256n (mf=2, nf=16 in QUARTERS of 4), acc[2][16].
// Phase 1: adj streamed sequentially (1KB/instr), ballot-compressed to
// bits[4][4][256] LDS. Phase 2: 32 windows x 32j, Bs quad-buffer gld_lds
// + vmcnt(2); af(win+1) built from LDS bits/E/F DURING win's MFMA quarters
// (inputs phase-1-static -> no staging dependence; VALU fills MFMA shadow).
__global__ __launch_bounds__(512, 1) void k_gatt19(const int* __restrict__ adjm,
                                                   const unsigned short* __restrict__ ht,
                                                   const float* __restrict__ mupart,
                                                   const float* __restrict__ xipart,
                                                   float* __restrict__ nump,
                                                   float* __restrict__ zpart) {
  __shared__ __align__(16) unsigned short Bs[4][256 * 32];       // 64 KB
  __shared__ __align__(16) unsigned long long bitsA[4][4][256];  // 32 KB
  __shared__ __align__(16) float EfE[1024];                      // 4 KB
  __shared__ __align__(16) float EfF[1024];                      // 4 KB

  int t = threadIdx.x, w = t >> 6, l = t & 63;
  int ln = l & 15, kg = l >> 4;
  int jb = blockIdx.x & 7, ig = blockIdx.x >> 3;
  int i0 = ig * 256;
  int jc0 = jb * 1024;

  // ---- prologue: xi -> exp staging (halves: t<256 does E, t>=256 does F) ----
  {
    int t2 = t & 255;
    float4 xa = *(const float4*)&xipart[jc0 + t2 * 4];
    float4 xb = *(const float4*)&xipart[8192 + jc0 + t2 * 4];
    float x0 = (xa.x + xb.x) * LOG2E, x1 = (xa.y + xb.y) * LOG2E;
    float x2 = (xa.z + xb.z) * LOG2E, x3 = (xa.w + xb.w) * LOG2E;
    if (t < 256) {
      EfE[t2 * 4 + 0] = __builtin_amdgcn_exp2f(x0);
      EfE[t2 * 4 + 1] = __builtin_amdgcn_exp2f(x1);
      EfE[t2 * 4 + 2] = __builtin_amdgcn_exp2f(x2);
      EfE[t2 * 4 + 3] = __builtin_amdgcn_exp2f(x3);
    } else {
      EfF[t2 * 4 + 0] = __builtin_amdgcn_exp2f(0.2f * x0);
      EfF[t2 * 4 + 1] = __builtin_amdgcn_exp2f(0.2f * x1);
      EfF[t2 * 4 + 2] = __builtin_amdgcn_exp2f(0.2f * x2);
      EfF[t2 * 4 + 3] = __builtin_amdgcn_exp2f(0.2f * x3);
    }
  }

  float EM[2], FM[2];
#pragma unroll
  for (int mf = 0; mf < 2; ++mf) {
    int i = i0 + w * 32 + mf * 16 + ln;
    float mu = (mupart[i] + mupart[8192 + i]) * LOG2E;
    EM[mf] = __builtin_amdgcn_exp2f(mu);
    FM[mf] = __builtin_amdgcn_exp2f(0.2f * mu);
  }

  floatx4 zero = {0.f, 0.f, 0.f, 0.f};
  floatx4 acc[2][16];
#pragma unroll
  for (int mf = 0; mf < 2; ++mf)
#pragma unroll
    for (int nf = 0; nf < 16; ++nf) acc[mf][nf] = zero;
  float zacc[2] = {0.f, 0.f};

  // Bs window: 256 n-rows x 32j; 2 gld_lds/wave. Source granule pre-swizzled
  // so reader slot kg^((n>>1)&3) yields granule kg.
#define STAGE_B(win_, b_)                                                   \
  {                                                                         \
    int j0_ = jc0 + (win_) * 32;                                            \
    _Pragma("unroll")                                                       \
    for (int q = 0; q < 2; ++q) {                                           \
      int rowbase = w * 32 + q * 16;                                        \
      int row = rowbase + (l >> 2);                                         \
      int g = (l & 3) ^ ((row >> 1) & 3);                                   \
      const void* gp = ht + (size_t)row * 8192 + j0_ + g * 8;               \
      int lb = __builtin_amdgcn_readfirstlane((b_) * (256 * 32) + rowbase * 32); \
      gld_lds16(gp, &((unsigned short*)Bs)[lb]);                            \
    }                                                                       \
  }

  // issue B stage(0,1) BEFORE phase 1 — lands during the adj stream
  STAGE_B(0, 0);
  STAGE_B(1, 1);

  // ---- PHASE 1: stream this wave's 32 adj rows sequentially, compress ----
  {
    const int* rp_base = adjm + (size_t)(i0 + w * 32) * 8192 + jc0;
    for (int r8 = 0; r8 < 32; ++r8) {
      const int* rp = rp_base + (size_t)r8 * 8192;
      // 4 chunks x 1KB contiguous (lane l: ints chunk*256 + 4l .. +3)
      int4 v0 = *(const int4*)(rp + 4 * l);
      int4 v1 = *(const int4*)(rp + 256 + 4 * l);
      int4 v2 = *(const int4*)(rp + 512 + 4 * l);
      int4 v3 = *(const int4*)(rp + 768 + 4 * l);
      int row = w * 32 + r8;
#define BALLOT4(vv, ch)                                                     \
      {                                                                     \
        unsigned long long b0 = __ballot(vv.x != 0);                        \
        unsigned long long b1 = __ballot(vv.y != 0);                        \
        unsigned long long b2 = __ballot(vv.z != 0);                        \
        unsigned long long b3 = __ballot(vv.w != 0);                        \
        if (l < 4) {                                                        \
          unsigned long long bs = (l == 0) ? b0 : (l == 1) ? b1             \
                                  : (l == 2) ? b2 : b3;                     \
          bitsA[ch][l][row] = bs;                                           \
        }                                                                   \
      }
      BALLOT4(v0, 0)
      BALLOT4(v1, 1)
      BALLOT4(v2, 2)
      BALLOT4(v3, 3)
#undef BALLOT4
    }
  }
  __syncthreads();  // E/F + bits + stage(0,1) all landed (one-time drain)

  // A-build for window win_, operand row set mf_, into dst_ (+ zacc once/win)
#define A_BUILD_MF(win_, mf_, dst_)                                         \
  {                                                                         \
    int jl_ = (win_) * 32 + kg * 8;                                         \
    float4 e0_ = *(const float4*)&EfE[jl_];                                 \
    float4 e1_ = *(const float4*)&EfE[jl_ + 4];                             \
    float4 f0_ = *(const float4*)&EfF[jl_];                                 \
    float4 f1_ = *(const float4*)&EfF[jl_ + 4];                             \
    int chunk_ = jl_ >> 8;                                                  \
    int p_ = (jl_ & 255) >> 2;                                              \
    int row_ = w * 32 + (mf_) * 16 + ln;                                    \
    unsigned long long q0_ = bitsA[chunk_][0][row_] >> p_;                  \
    unsigned long long q1_ = bitsA[chunk_][1][row_] >> p_;                  \
    unsigned long long q2_ = bitsA[chunk_][2][row_] >> p_;                  \
    unsigned long long q3_ = bitsA[chunk_][3][row_] >> p_;                  \
    float ex_[8] = {e0_.x, e0_.y, e0_.z, e0_.w, e1_.x, e1_.y, e1_.z, e1_.w};\
    float fx_[8] = {f0_.x, f0_.y, f0_.z, f0_.w, f1_.x, f1_.y, f1_.z, f1_.w};\
    int av_[8];                                                             \
    av_[0] = (int)(q0_ & 1); av_[1] = (int)(q1_ & 1);                       \
    av_[2] = (int)(q2_ & 1); av_[3] = (int)(q3_ & 1);                       \
    av_[4] = (int)((q0_ >> 1) & 1); av_[5] = (int)((q1_ >> 1) & 1);         \
    av_[6] = (int)((q2_ >> 1) & 1); av_[7] = (int)((q3_ >> 1) & 1);         \
    float A_ = EM[mf_], F_ = FM[mf_];                                       \
    union { unsigned u[4]; short8 s; } cv_;                                 \
    float zs_ = 0.f;                                                        \
    _Pragma("unroll")                                                       \
    for (int pp = 0; pp < 4; ++pp) {                                        \
      float m0_ = fmaxf(A_ * ex_[2 * pp], F_ * fx_[2 * pp]);                \
      float m1_ = fmaxf(A_ * ex_[2 * pp + 1], F_ * fx_[2 * pp + 1]);        \
      m0_ = (av_[2 * pp] != 0) ? m0_ : 0.f;                                 \
      m1_ = (av_[2 * pp + 1] != 0) ? m1_ : 0.f;                             \
      zs_ += m0_;                                                           \
      zs_ += m1_;                                                           \
      cv_.u[pp] = cvtpk_bf16(m0_, m1_);                                     \
    }                                                                       \
    zacc[mf_] += zs_;                                                       \
    (dst_) = cv_.s;                                                         \
  }

  // MFMA quarter qtr_ consuming afc
#define QTR(qtr_)                                                           \
    {                                                                       \
      short8 bfv[4];                                                        \
      _Pragma("unroll")                                                     \
      for (int nf = 0; nf < 4; ++nf) {                                      \
        int n = (qtr_) * 64 + nf * 16 + ln;                                 \
        bfv[nf] = *(const short8*)&Bs[bR][n * 32 + ((kg ^ ((n >> 1) & 3)) * 8)]; \
      }                                                                     \
      _Pragma("unroll")                                                     \
      for (int mf = 0; mf < 2; ++mf)                                        \
        _Pragma("unroll")                                                   \
        for (int nf = 0; nf < 4; ++nf)                                      \
          acc[mf][(qtr_) * 4 + nf] = __builtin_amdgcn_mfma_f32_16x16x32_bf16( \
              afc[mf], bfv[nf], acc[mf][(qtr_) * 4 + nf], 0, 0, 0);         \
    }

  short8 afc[2], afn[2];
  A_BUILD_MF(0, 0, afc[0]);
  A_BUILD_MF(0, 1, afc[1]);
  afn[0] = afc[0];
  afn[1] = afc[1];

  // ---- PHASE 2: window loop; af(win+1) built during win's MFMAs ----
  for (int win = 0; win < 32; ++win) {
    int bR = win & 3;
    // stage(win) landed; stage(win+1) stays in flight
    if (win < 31) {
      asm volatile("s_waitcnt vmcnt(2)" ::: "memory");
    } else {
      asm volatile("s_waitcnt vmcnt(0)" ::: "memory");
    }
    __builtin_amdgcn_s_barrier();   // all waves' stage(win) landed
    asm volatile("" ::: "memory");  // fence: no LDS reads hoist above barrier

    QTR(0)
    if (win < 31) A_BUILD_MF(win + 1, 0, afn[0])
    QTR(1)
    QTR(2)
    if (win < 31) A_BUILD_MF(win + 1, 1, afn[1])
    QTR(3)
    // issue next-next window staging (write target 2 windows from readers)
    if (win < 30) {
      STAGE_B(win + 2, (win + 2) & 3);
    }
    afc[0] = afn[0];
    afc[1] = afn[1];
  }
#undef QTR
#undef A_BUILD_MF
#undef STAGE_B

  // ---- epilogue: z partial (reduce over kg lanes) ----
#pragma unroll
  for (int mf = 0; mf < 2; ++mf) {
    float z = zacc[mf];
    z += __shfl_xor(z, 16);
    z += __shfl_xor(z, 32);
    if (l < 16) zpart[(size_t)jb * 8192 + i0 + w * 32 + mf * 16 + ln] = z;
  }

  // ---- epilogue: numerator partial (plain stores) ----
  float* np = nump + (size_t)jb * (8192 * 256);
#pragma unroll
  for (int mf = 0; mf < 2; ++mf) {
    int rowb = i0 + w * 32 + mf * 16 + kg * 4;
#pragma unroll
    for (int r = 0; r < 4; ++r) {
      float* rp = np + (size_t)(rowb + r) * 256;
#pragma unroll
      for (int nf = 0; nf < 16; ++nf)
        rp[nf * 16 + ln] = acc[mf][nf][r];
    }
  }
}

// ---------------- K4: finalize: sum 8 j-partials, /Z, ELU -------------------
__global__ void k_final(const float* __restrict__ nump, const float* __restrict__ zpart,
                        float* __restrict__ out) {
  int tid = blockIdx.x * 256 + threadIdx.x;  // x4 floats
  int i = tid >> 6;
  float z = 0.f;
#pragma unroll
  for (int p = 0; p < 8; ++p) z += zpart[(size_t)p * 8192 + i];
  float zi = 1.0f / z;
  float4 v = {0.f, 0.f, 0.f, 0.f};
#pragma unroll
  for (int p = 0; p < 8; ++p) {
    float4 s = *(const float4*)&nump[(size_t)p * (8192 * 256) + tid * 4];
    v.x += s.x; v.y += s.y; v.z += s.z; v.w += s.w;
  }
  v.x *= zi; v.y *= zi; v.z *= zi; v.w *= zi;
  v.x = (v.x > 0.f) ? v.x : (__builtin_amdgcn_exp2f(v.x * LOG2E) - 1.f);
  v.y = (v.y > 0.f) ? v.y : (__builtin_amdgcn_exp2f(v.y * LOG2E) - 1.f);
  v.z = (v.z > 0.f) ? v.z : (__builtin_amdgcn_exp2f(v.z * LOG2E) - 1.f);
  v.w = (v.w > 0.f) ? v.w : (__builtin_amdgcn_exp2f(v.w * LOG2E) - 1.f);
  *(float4*)&out[tid * 4] = v;
}

// ---------------------------------------------------------------------------
extern "C" void kernel_launch(void* const* d_in, const int* in_sizes, int n_in,
                              void* d_out, int out_size, void* d_ws, size_t ws_size,
                              hipStream_t stream) {
  const float* features = (const float*)d_in[0];
  const int* adjm = (const int*)d_in[1];
  const float* W_phi = (const float*)d_in[2];
  const float* w_mu = (const float*)d_in[3];
  const float* w_xi = (const float*)d_in[4];
  float* out = (float*)d_out;

  char* ws = (char*)d_ws;
  unsigned short* ht  = (unsigned short*)(ws + 0);         // 256x8192 bf16 = 4 MB
  unsigned short* wt  = (unsigned short*)(ws + 4194304);   // 256x512 bf16 = 256 KB
  float* mupart = (float*)(ws + 4456448);                  // 2x8192 f32 = 64 KB
  float* xipart = (float*)(ws + 4521984);                  // 2x8192 f32 = 64 KB
  float* zpart  = (float*)(ws + 4587520);                  // 8x8192 f32 = 256 KB
  float* nump   = (float*)(ws + 8388608);                  // 8 x 8 MB partials

  k_prep_wt<<<512, 256, 0, stream>>>(W_phi, wt);
  k_gemm1m<<<256, 256, 0, stream>>>(features, wt, w_mu, w_xi, ht, mupart, xipart);
  k_gatt19<<<256, 512, 0, stream>>>(adjm, ht, mupart, xipart, nump, zpart);
  k_final<<<2048, 256, 0, stream>>>(nump, zpart, out);
}